// Round 1
// baseline (191.600 us; speedup 1.0000x reference)
//
#include <hip/hip_runtime.h>
#include <stdint.h>
#include <stddef.h>

constexpr int kNodes = 50000;
constexpr int kEdges = 500000;
constexpr int kD     = 128;   // per-half feature dim
constexpr int kC     = 64;    // out classes
constexpr int kK     = 256;   // W row length = 2*kD

typedef __attribute__((ext_vector_type(8))) short  short8;   // 8 x bf16
typedef __attribute__((ext_vector_type(4))) float  floatx4;  // MFMA C/D + vec IO

__device__ __forceinline__ unsigned short f2bf(float f) {
  union { float f; unsigned u; } v; v.f = f;
  unsigned u = v.u;
  unsigned r = u + 0x7FFFu + ((u >> 16) & 1u);
  return (unsigned short)(r >> 16);
}

__device__ __forceinline__ float bf2f(short s) {
  union { unsigned u; float f; } v;
  v.u = ((unsigned)(unsigned short)s) << 16;
  return v.f;
}

__device__ __forceinline__ short8 cvt8(floatx4 a, floatx4 b) {
  short8 r;
  r[0] = (short)f2bf(a[0]); r[1] = (short)f2bf(a[1]);
  r[2] = (short)f2bf(a[2]); r[3] = (short)f2bf(a[3]);
  r[4] = (short)f2bf(b[0]); r[5] = (short)f2bf(b[1]);
  r[6] = (short)f2bf(b[2]); r[7] = (short)f2bf(b[3]);
  return r;
}

// ---------------------------------------------------------------------------
// Kernel 1: node GEMM.  P = h @ [W_u^T | W_v^T] (50000 x 128); first 64 cols
// get +b. Stored bf16 into Pu / Pv. h read sequentially (no gather), via
// nontemporal loads (single-use stream; keep L2 for W + tables).
// ---------------------------------------------------------------------------
__global__ __launch_bounds__(256)
void node_gemm_kernel(const float* __restrict__ h,
                      const float* __restrict__ W,
                      const float* __restrict__ b,
                      unsigned short* __restrict__ Pu,
                      unsigned short* __restrict__ Pv) {
  __shared__ short8 Blds[2048];  // (kstep*8 + ntile)*64 + lane ; 32 KiB

  const int tid = threadIdx.x;

  // Stage W -> LDS in B-fragment order (stacked cols: 0..63 = W_u, 64..127 = W_v)
  for (int s = tid; s < 2048; s += 256) {
    int kstep = s >> 9;         // 0..3
    int ntile = (s >> 6) & 7;   // 0..7
    int ln    = s & 63;
    int np = ntile * 16 + (ln & 15);
    int k  = kstep * 32 + (ln >> 4) * 8;
    int wc = (np < kC) ? np : (np - kC);
    int wk = (np < kC) ? k  : (k + kD);
    const float* wp = W + wc * kK + wk;
    Blds[s] = cvt8(*reinterpret_cast<const floatx4*>(wp),
                   *reinterpret_cast<const floatx4*>(wp + 4));
  }

  const int lane = tid & 63;
  const int wave = tid >> 6;
  const int rowA = lane & 15;
  const int quad = lane >> 4;
  const int col  = rowA;

  const int rowbase = blockIdx.x * 128 + wave * 32;
  int n0 = rowbase + rowA;       if (n0 >= kNodes) n0 = kNodes - 1;
  int n1 = rowbase + 16 + rowA;  if (n1 >= kNodes) n1 = kNodes - 1;

  short8 a0[4], a1[4];
#pragma unroll
  for (int kstep = 0; kstep < 4; ++kstep) {
    const float* p0 = h + (size_t)n0 * kD + kstep * 32 + quad * 8;
    const float* p1 = h + (size_t)n1 * kD + kstep * 32 + quad * 8;
    a0[kstep] = cvt8(__builtin_nontemporal_load(reinterpret_cast<const floatx4*>(p0)),
                     __builtin_nontemporal_load(reinterpret_cast<const floatx4*>(p0 + 4)));
    a1[kstep] = cvt8(__builtin_nontemporal_load(reinterpret_cast<const floatx4*>(p1)),
                     __builtin_nontemporal_load(reinterpret_cast<const floatx4*>(p1 + 4)));
  }

  floatx4 acc0[8], acc1[8];
#pragma unroll
  for (int nt = 0; nt < 8; ++nt) {
    acc0[nt] = (floatx4){0.f, 0.f, 0.f, 0.f};
    acc1[nt] = (floatx4){0.f, 0.f, 0.f, 0.f};
  }

  __syncthreads();

#pragma unroll
  for (int kstep = 0; kstep < 4; ++kstep) {
#pragma unroll
    for (int nt = 0; nt < 8; ++nt) {
      short8 bfrag = Blds[(kstep * 8 + nt) * 64 + lane];
      acc0[nt] = __builtin_amdgcn_mfma_f32_16x16x32_bf16(a0[kstep], bfrag,
                                                         acc0[nt], 0, 0, 0);
      acc1[nt] = __builtin_amdgcn_mfma_f32_16x16x32_bf16(a1[kstep], bfrag,
                                                         acc1[nt], 0, 0, 0);
    }
  }

  // Epilogue: C/D layout col=lane&15, row=quad*4+reg [m89/m91].
  const bool full = (rowbase + 32) <= kNodes;  // wave-uniform
#pragma unroll
  for (int nt = 0; nt < 4; ++nt) {
    float bv = b[nt * 16 + col];
#pragma unroll
    for (int r = 0; r < 4; ++r) {
      int ra = rowbase + quad * 4 + r;
      int rb = ra + 16;
      if (full || ra < kNodes)
        Pu[(size_t)ra * kC + nt * 16 + col] = f2bf(acc0[nt][r] + bv);
      if (full || rb < kNodes)
        Pu[(size_t)rb * kC + nt * 16 + col] = f2bf(acc1[nt][r] + bv);
    }
  }
#pragma unroll
  for (int nt = 4; nt < 8; ++nt) {
#pragma unroll
    for (int r = 0; r < 4; ++r) {
      int ra = rowbase + quad * 4 + r;
      int rb = ra + 16;
      if (full || ra < kNodes)
        Pv[(size_t)ra * kC + (nt - 4) * 16 + col] = f2bf(acc0[nt][r]);
      if (full || rb < kNodes)
        Pv[(size_t)rb * kC + (nt - 4) * 16 + col] = f2bf(acc1[nt][r]);
    }
  }
}

// ---------------------------------------------------------------------------
// Kernel 2: edge combine.  out[e,:] = f32(Pu[src[e],:]) + f32(Pv[dst[e],:]).
// Wave handles 64 consecutive edges in 8 passes of 8 edges; 8 lanes/edge.
// Indices: 2 coalesced nontemporal loads per lane + __shfl distribution
// (replaces 16 redundant same-address loads -> one early vmcnt wait).
// All 16 gather loads (cached: tables have ~10x reuse) issued before use.
// Output: nontemporal float4 stores -- the 128 MB stream must not evict the
// 12.8 MB Pu/Pv tables from L2 (gather latency protection).
// ---------------------------------------------------------------------------
__global__ __launch_bounds__(256)
void edge_combine_kernel(const unsigned short* __restrict__ Pu,
                         const unsigned short* __restrict__ Pv,
                         const int* __restrict__ src,
                         const int* __restrict__ dst,
                         float* __restrict__ out) {
  const int tid  = threadIdx.x;
  const int lane = tid & 63;
  const int g    = lane & 7;          // col group: cols 8g..8g+7
  const int er8  = lane >> 3;         // edge-within-pass 0..7
  const int wave = tid >> 6;
  const long wbase = (long)blockIdx.x * 256 + (long)wave * 64;

  // Per-lane index ownership (coalesced streaming loads, clamped for tail).
  long eown = wbase + lane;
  if (eown >= kEdges) eown = kEdges - 1;
  const int si_own = __builtin_nontemporal_load(src + eown);
  const int di_own = __builtin_nontemporal_load(dst + eown);

  // Distribute: gather-owner lane (er8,g) needs index of edge wbase+j*8+er8.
  int sg[8], dg[8];
#pragma unroll
  for (int j = 0; j < 8; ++j) {
    sg[j] = __shfl(si_own, j * 8 + er8, 64);
    dg[j] = __shfl(di_own, j * 8 + er8, 64);
  }

  // Issue all 16 gathers before any use (latency hiding). 8 lanes/edge read
  // one full 128-B line per table, coalesced.
  short8 pu[8], pv[8];
#pragma unroll
  for (int j = 0; j < 8; ++j) {
    pu[j] = *reinterpret_cast<const short8*>(
        Pu + (((size_t)(unsigned)sg[j]) << 6) + g * 8);
    pv[j] = *reinterpret_cast<const short8*>(
        Pv + (((size_t)(unsigned)dg[j]) << 6) + g * 8);
  }

  const bool full = (wbase + 64) <= (long)kEdges;  // wave-uniform
#pragma unroll
  for (int j = 0; j < 8; ++j) {
    const long e = wbase + j * 8 + er8;
    floatx4 o0, o1;
    o0[0] = bf2f(pu[j][0]) + bf2f(pv[j][0]);
    o0[1] = bf2f(pu[j][1]) + bf2f(pv[j][1]);
    o0[2] = bf2f(pu[j][2]) + bf2f(pv[j][2]);
    o0[3] = bf2f(pu[j][3]) + bf2f(pv[j][3]);
    o1[0] = bf2f(pu[j][4]) + bf2f(pv[j][4]);
    o1[1] = bf2f(pu[j][5]) + bf2f(pv[j][5]);
    o1[2] = bf2f(pu[j][6]) + bf2f(pv[j][6]);
    o1[3] = bf2f(pu[j][7]) + bf2f(pv[j][7]);
    if (full || e < kEdges) {
      float* op = out + e * (long)kC + g * 8;
      __builtin_nontemporal_store(o0, reinterpret_cast<floatx4*>(op));
      __builtin_nontemporal_store(o1, reinterpret_cast<floatx4*>(op + 4));
    }
  }
}

extern "C" void kernel_launch(void* const* d_in, const int* in_sizes, int n_in,
                              void* d_out, int out_size, void* d_ws, size_t ws_size,
                              hipStream_t stream) {
  const float* h   = (const float*)d_in[0];
  const int*   src = (const int*)  d_in[1];
  const int*   dst = (const int*)  d_in[2];
  const float* W   = (const float*)d_in[3];
  const float* b   = (const float*)d_in[4];
  float*       out = (float*)d_out;

  // Workspace: Pu (50000x64 bf16) | Pv (50000x64 bf16) = 12.8 MB total.
  const size_t tbl = (size_t)kNodes * kC * sizeof(unsigned short);  // 6.4 MB
  unsigned short* Pu = (unsigned short*)d_ws;
  unsigned short* Pv = (unsigned short*)((char*)d_ws + tbl);        // 16B-aligned

  const int gemm_grid = (kNodes + 127) / 128;   // 391
  const int edge_grid = (kEdges + 255) / 256;   // 1954

  node_gemm_kernel<<<gemm_grid, 256, 0, stream>>>(h, W, b, Pu, Pv);
  edge_combine_kernel<<<edge_grid, 256, 0, stream>>>(Pu, Pv, src, dst, out);
}

// Round 2
// 185.812 us; speedup vs baseline: 1.0311x; 1.0311x over previous
//
#include <hip/hip_runtime.h>
#include <stdint.h>
#include <stddef.h>

constexpr int kNodes = 50000;
constexpr int kEdges = 500000;
constexpr int kD     = 128;   // per-half feature dim
constexpr int kC     = 64;    // out classes
constexpr int kK     = 256;   // W row length = 2*kD
constexpr int kP     = 128;   // P table row length (Pu | Pv)

typedef __attribute__((ext_vector_type(8))) short  short8;   // 8 x bf16
typedef __attribute__((ext_vector_type(4))) float  floatx4;  // MFMA C/D + vec IO

__device__ __forceinline__ unsigned short f2bf(float f) {
  union { float f; unsigned u; } v; v.f = f;
  unsigned u = v.u;
  unsigned r = u + 0x7FFFu + ((u >> 16) & 1u);
  return (unsigned short)(r >> 16);
}

__device__ __forceinline__ float bf2f(short s) {
  union { unsigned u; float f; } v;
  v.u = ((unsigned)(unsigned short)s) << 16;
  return v.f;
}

__device__ __forceinline__ short8 cvt8(floatx4 a, floatx4 b) {
  short8 r;
  r[0] = (short)f2bf(a[0]); r[1] = (short)f2bf(a[1]);
  r[2] = (short)f2bf(a[2]); r[3] = (short)f2bf(a[3]);
  r[4] = (short)f2bf(b[0]); r[5] = (short)f2bf(b[1]);
  r[6] = (short)f2bf(b[2]); r[7] = (short)f2bf(b[3]);
  return r;
}

// ---------------------------------------------------------------------------
// Kernel 1: node GEMM.  P[n, 0:64]  = (h @ W_u^T)[n] + b   (bf16)
//           P[n,64:128] = (h @ W_v^T)[n]                    (bf16)
// Block = 256 thr = 4 waves; 16 rows/wave, 64 rows/block, grid = 782.
// Epilogue: MFMA C-layout (col=lane&15, row=quad*4+r) is bounced through LDS
// (ds_write_b16 -> ds_read_b128) so global stores are 16-B contiguous chunks
// of a 256-B row -- replaces the previous 64 scattered 2-B stores per lane.
// ---------------------------------------------------------------------------
__global__ __launch_bounds__(256)
void node_gemm_kernel(const float* __restrict__ h,
                      const float* __restrict__ W,
                      const float* __restrict__ b,
                      unsigned short* __restrict__ P) {
  __shared__ short8 Blds[2048];                       // 32 KiB, B fragments
  __shared__ __align__(16) unsigned short ep[4][16][136];  // 17 KiB (+8 pad)

  const int tid = threadIdx.x;

  // Stage W -> LDS in B-fragment order (stacked cols: 0..63 = W_u, 64..127 = W_v)
  for (int s = tid; s < 2048; s += 256) {
    int kstep = s >> 9;         // 0..3
    int ntile = (s >> 6) & 7;   // 0..7
    int ln    = s & 63;
    int np = ntile * 16 + (ln & 15);
    int k  = kstep * 32 + (ln >> 4) * 8;
    int wc = (np < kC) ? np : (np - kC);
    int wk = (np < kC) ? k  : (k + kD);
    const float* wp = W + wc * kK + wk;
    Blds[s] = cvt8(*reinterpret_cast<const floatx4*>(wp),
                   *reinterpret_cast<const floatx4*>(wp + 4));
  }

  const int lane  = tid & 63;
  const int wave  = tid >> 6;
  const int rowA  = lane & 15;
  const int quad  = lane >> 4;
  const int col16 = rowA;

  const int rowbase = blockIdx.x * 64 + wave * 16;
  int n0 = rowbase + rowA;  if (n0 >= kNodes) n0 = kNodes - 1;

  short8 a0[4];
#pragma unroll
  for (int kstep = 0; kstep < 4; ++kstep) {
    const float* p0 = h + (size_t)n0 * kD + kstep * 32 + quad * 8;
    a0[kstep] = cvt8(__builtin_nontemporal_load(reinterpret_cast<const floatx4*>(p0)),
                     __builtin_nontemporal_load(reinterpret_cast<const floatx4*>(p0 + 4)));
  }

  floatx4 acc[8];
#pragma unroll
  for (int nt = 0; nt < 8; ++nt) acc[nt] = (floatx4){0.f, 0.f, 0.f, 0.f};

  __syncthreads();

#pragma unroll
  for (int kstep = 0; kstep < 4; ++kstep) {
#pragma unroll
    for (int nt = 0; nt < 8; ++nt) {
      short8 bfrag = Blds[(kstep * 8 + nt) * 64 + lane];
      acc[nt] = __builtin_amdgcn_mfma_f32_16x16x32_bf16(a0[kstep], bfrag,
                                                        acc[nt], 0, 0, 0);
    }
  }

  // ---- Epilogue: acc -> LDS (bf16, row-major, +8 ushort pad) ----
  // C/D layout: col = lane&15, row = quad*4 + r  [m89/m91].
#pragma unroll
  for (int nt = 0; nt < 4; ++nt) {
    float bv = b[nt * 16 + col16];
#pragma unroll
    for (int r = 0; r < 4; ++r)
      ep[wave][quad * 4 + r][nt * 16 + col16] = f2bf(acc[nt][r] + bv);
  }
#pragma unroll
  for (int nt = 4; nt < 8; ++nt) {
#pragma unroll
    for (int r = 0; r < 4; ++r)
      ep[wave][quad * 4 + r][nt * 16 + col16] = f2bf(acc[nt][r]);
  }

  // ---- LDS -> global, 16-B chunks (wave-local, no barrier needed) ----
  // 16 rows x 128 cols = 256 chunks of 8 ushorts; lane handles 4.
#pragma unroll
  for (int c = 0; c < 4; ++c) {
    int i   = c * 64 + lane;
    int row = i >> 4;          // 0..15
    int g   = i & 15;          // col group: cols 8g..8g+7 of 128
    int grow = rowbase + row;
    if (grow < kNodes) {
      short8 v = *reinterpret_cast<const short8*>(&ep[wave][row][g * 8]);
      *reinterpret_cast<short8*>(P + (size_t)grow * kP + g * 8) = v;
    }
  }
}

// ---------------------------------------------------------------------------
// Kernel 2: edge combine.  out[e,:] = f32(P[src[e],0:64]) + f32(P[dst[e],64:128]).
// Wave handles 64 consecutive edges in 8 passes of 8 edges; 8 lanes/edge.
// Indices: 2 coalesced nontemporal loads per lane + __shfl distribution.
// All 16 gather loads (cached: table has ~20x reuse) issued before use.
// Output: nontemporal float4 stores (128 MB stream; don't evict the table).
// ---------------------------------------------------------------------------
__global__ __launch_bounds__(256)
void edge_combine_kernel(const unsigned short* __restrict__ P,
                         const int* __restrict__ src,
                         const int* __restrict__ dst,
                         float* __restrict__ out) {
  const int tid  = threadIdx.x;
  const int lane = tid & 63;
  const int g    = lane & 7;          // col group: cols 8g..8g+7
  const int er8  = lane >> 3;         // edge-within-pass 0..7
  const int wave = tid >> 6;
  const long wbase = (long)blockIdx.x * 256 + (long)wave * 64;

  // Per-lane index ownership (coalesced streaming loads, clamped for tail).
  long eown = wbase + lane;
  if (eown >= kEdges) eown = kEdges - 1;
  const int si_own = __builtin_nontemporal_load(src + eown);
  const int di_own = __builtin_nontemporal_load(dst + eown);

  // Distribute: gather-owner lane (er8,g) needs index of edge wbase+j*8+er8.
  int sg[8], dg[8];
#pragma unroll
  for (int j = 0; j < 8; ++j) {
    sg[j] = __shfl(si_own, j * 8 + er8, 64);
    dg[j] = __shfl(di_own, j * 8 + er8, 64);
  }

  // Issue all 16 gathers before any use (latency hiding). 8 lanes/edge read
  // one 128-B half-row per operand, coalesced into single-line requests.
  short8 pu[8], pv[8];
#pragma unroll
  for (int j = 0; j < 8; ++j) {
    pu[j] = *reinterpret_cast<const short8*>(
        P + (((size_t)(unsigned)sg[j]) << 7) + g * 8);
    pv[j] = *reinterpret_cast<const short8*>(
        P + (((size_t)(unsigned)dg[j]) << 7) + 64 + g * 8);
  }

  const bool full = (wbase + 64) <= (long)kEdges;  // wave-uniform
#pragma unroll
  for (int j = 0; j < 8; ++j) {
    const long e = wbase + j * 8 + er8;
    floatx4 o0, o1;
    o0[0] = bf2f(pu[j][0]) + bf2f(pv[j][0]);
    o0[1] = bf2f(pu[j][1]) + bf2f(pv[j][1]);
    o0[2] = bf2f(pu[j][2]) + bf2f(pv[j][2]);
    o0[3] = bf2f(pu[j][3]) + bf2f(pv[j][3]);
    o1[0] = bf2f(pu[j][4]) + bf2f(pv[j][4]);
    o1[1] = bf2f(pu[j][5]) + bf2f(pv[j][5]);
    o1[2] = bf2f(pu[j][6]) + bf2f(pv[j][6]);
    o1[3] = bf2f(pu[j][7]) + bf2f(pv[j][7]);
    if (full || e < kEdges) {
      float* op = out + e * (long)kC + g * 8;
      __builtin_nontemporal_store(o0, reinterpret_cast<floatx4*>(op));
      __builtin_nontemporal_store(o1, reinterpret_cast<floatx4*>(op + 4));
    }
  }
}

extern "C" void kernel_launch(void* const* d_in, const int* in_sizes, int n_in,
                              void* d_out, int out_size, void* d_ws, size_t ws_size,
                              hipStream_t stream) {
  const float* h   = (const float*)d_in[0];
  const int*   src = (const int*)  d_in[1];
  const int*   dst = (const int*)  d_in[2];
  const float* W   = (const float*)d_in[3];
  const float* b   = (const float*)d_in[4];
  float*       out = (float*)d_out;

  // Workspace: P (50000 x 128 bf16, Pu|Pv interleaved) = 12.8 MB.
  unsigned short* P = (unsigned short*)d_ws;

  const int gemm_grid = (kNodes + 63) / 64;     // 782
  const int edge_grid = (kEdges + 255) / 256;   // 1954

  node_gemm_kernel<<<gemm_grid, 256, 0, stream>>>(h, W, b, P);
  edge_combine_kernel<<<edge_grid, 256, 0, stream>>>(P, src, dst, out);
}